// Round 1
// baseline (1079.350 us; speedup 1.0000x reference)
//
#include <hip/hip_runtime.h>

#define B_ 2
#define S_ 2048
#define E_ 4096
#define NH 32
#define NKV 8
#define DH 128

typedef __attribute__((ext_vector_type(8))) short short8;   // 8 x bf16 (4 VGPRs)
typedef __attribute__((ext_vector_type(4))) float f32x4;    // MFMA 16x16 accumulator

__device__ __forceinline__ unsigned short f2bf(float f) {
  unsigned int u = __float_as_uint(f);
  u += 0x7fffu + ((u >> 16) & 1u);   // RNE
  return (unsigned short)(u >> 16);
}
__device__ __forceinline__ float bf2f(unsigned short u) {
  return __uint_as_float(((unsigned int)u) << 16);
}

// async global->LDS, 16B per lane. LDS dest = wave-uniform base + lane*16.
__device__ __forceinline__ void async16(const void* g, void* l) {
  __builtin_amdgcn_global_load_lds(
      (__attribute__((address_space(1))) void*)const_cast<void*>(g),
      (__attribute__((address_space(3))) void*)l, 16, 0, 0);
}

// ---------------- fp32 -> bf16 elementwise ----------------
__global__ void k_cvt(const float4* __restrict__ in, ushort4* __restrict__ out, int n4) {
  int i = blockIdx.x * blockDim.x + threadIdx.x;
  if (i >= n4) return;
  float4 v = in[i];
  ushort4 o;
  o.x = f2bf(v.x); o.y = f2bf(v.y); o.z = f2bf(v.z); o.w = f2bf(v.w);
  out[i] = o;
}

// ---------------- W (KxN fp32, row-major) -> out (NxK bf16) ----------------
__global__ void k_transpose(const float* __restrict__ in, unsigned short* __restrict__ out,
                            int K, int N) {
  __shared__ float tile[32][33];
  int n0 = blockIdx.x * 32, k0 = blockIdx.y * 32;
  int tx = threadIdx.x, ty = threadIdx.y;  // 32 x 8
#pragma unroll
  for (int j = 0; j < 32; j += 8)
    tile[ty + j][tx] = in[(size_t)(k0 + ty + j) * N + n0 + tx];
  __syncthreads();
#pragma unroll
  for (int j = 0; j < 32; j += 8)
    out[(size_t)(n0 + ty + j) * K + k0 + tx] = f2bf(tile[tx][ty + j]);
}

// ---------------- RoPE in-place on (B, heads, S, D) bf16 ----------------
__global__ void k_rope(unsigned short* buf, int heads, const int* __restrict__ pos) {
  int i = blockIdx.x * blockDim.x + threadIdx.x;
  int d = i & 63;
  int s = (i >> 6) & (S_ - 1);
  int bh = i >> 17;                 // S_*64 = 2^17 per (b,head)
  int b = bh / heads;
  float p = (float)pos[b * S_ + s];
  // inv_freq = 10000^(-d/64);  ln(10000)/64 = 0.14391156831212787
  float fr = p * expf(-0.14391156831212787f * (float)d);
  float c, sn;
  sincosf(fr, &sn, &c);
  size_t base = ((size_t)bh * S_ + s) * DH;
  float x1 = bf2f(buf[base + d]);
  float x2 = bf2f(buf[base + d + 64]);
  buf[base + d]      = f2bf(x1 * c - x2 * sn);
  buf[base + d + 64] = f2bf(x2 * c + x1 * sn);
}

// ---------------- GEMM: A(MxK bf16 row-major) x Bt(NxK bf16) ----------------
// MODE 0: QKV epilogue (bias + scatter to Q/K/V^T bf16).  MODE 1: plain fp32 C.
template <int MODE>
__global__ __launch_bounds__(256) void k_gemm(
    const unsigned short* __restrict__ A, const unsigned short* __restrict__ Bt, int K,
    const float* __restrict__ bq, const float* __restrict__ bk, const float* __restrict__ bv,
    unsigned short* __restrict__ Qo, unsigned short* __restrict__ Ko,
    unsigned short* __restrict__ Vo, float* __restrict__ Co) {
  __shared__ unsigned short As[128 * 32];
  __shared__ unsigned short Bs[128 * 32];
  const int tid = threadIdx.x;
  const int wave = tid >> 6, lane = tid & 63;
  const int l15 = lane & 15, quad = lane >> 4;
  const int m0 = blockIdx.y * 128, n0 = blockIdx.x * 128;
  const int wm = (wave & 1) * 64, wn = (wave >> 1) * 64;

  f32x4 acc[4][4] = {};
  const int e0 = wave * 64 + lane;

  for (int k0 = 0; k0 < K; k0 += 32) {
#pragma unroll
    for (int r = 0; r < 2; ++r) {
      int e = r * 256 + e0;
      int row = e >> 2, seg = e & 3;
      async16(A + (size_t)(m0 + row) * K + k0 + seg * 8, &As[(size_t)(r * 256 + wave * 64) * 8]);
      async16(Bt + (size_t)(n0 + row) * K + k0 + seg * 8, &Bs[(size_t)(r * 256 + wave * 64) * 8]);
    }
    __syncthreads();
    short8 af[4], bfr[4];
#pragma unroll
    for (int i = 0; i < 4; ++i)
      af[i] = *(const short8*)&As[(wm + i * 16 + l15) * 32 + quad * 8];
#pragma unroll
    for (int i = 0; i < 4; ++i)
      bfr[i] = *(const short8*)&Bs[(wn + i * 16 + l15) * 32 + quad * 8];
#pragma unroll
    for (int mi = 0; mi < 4; ++mi)
#pragma unroll
      for (int ni = 0; ni < 4; ++ni)
        acc[mi][ni] = __builtin_amdgcn_mfma_f32_16x16x32_bf16(af[mi], bfr[ni], acc[mi][ni], 0, 0, 0);
    __syncthreads();
  }

#pragma unroll
  for (int mi = 0; mi < 4; ++mi) {
#pragma unroll
    for (int ni = 0; ni < 4; ++ni) {
      const int col = n0 + wn + ni * 16 + l15;
      const int rowb = m0 + wm + mi * 16 + quad * 4;
      if constexpr (MODE == 1) {
#pragma unroll
        for (int r = 0; r < 4; ++r)
          Co[(size_t)(rowb + r) * E_ + col] = acc[mi][ni][r];
      } else {
#pragma unroll
        for (int r = 0; r < 4; ++r) {
          const int row = rowb + r;
          const int b = row >> 11, s = row & (S_ - 1);
          float v = acc[mi][ni][r];
          if (col < 4096) {           // Q: (B,NH,S,D)
            v += bq[col];
            const int h = col >> 7, d = col & 127;
            Qo[(((size_t)b * NH + h) * S_ + s) * DH + d] = f2bf(v);
          } else if (col < 5120) {    // K: (B,NKV,S,D)
            const int t = col - 4096;
            v += bk[t];
            const int h = t >> 7, d = t & 127;
            Ko[(((size_t)b * NKV + h) * S_ + s) * DH + d] = f2bf(v);
          } else {                    // V^T: (B,NKV,D,S)
            const int t = col - 5120;
            v += bv[t];
            const int h = t >> 7, d = t & 127;
            Vo[(((size_t)b * NKV + h) * DH + d) * S_ + s] = f2bf(v);
          }
        }
      }
    }
  }
}

// ---------------- flash attention: Br=64, Bc=128, causal ----------------
// Q (B,NH,S,D), K (B,NKV,S,D), Vt (B,NKV,D,S) -> O (B,S,NH,D)   all bf16
__global__ __launch_bounds__(256) void k_attn(
    const unsigned short* __restrict__ Q, const unsigned short* __restrict__ Kb,
    const unsigned short* __restrict__ Vt, unsigned short* __restrict__ O) {
  __shared__ unsigned short Ks[128 * 128];  // 32KB, xor-swizzled 16B slots
  __shared__ unsigned short Vs[128 * 128];  // 32KB
  __shared__ unsigned short Ps[64 * 128];   // 16KB, per-wave 16 rows
  const int tid = threadIdx.x;
  const int wave = tid >> 6, lane = tid & 63;
  const int l15 = lane & 15, quad = lane >> 4;
  const int bid = blockIdx.x;
  const int qt = bid & 31;          // S/64
  const int h = (bid >> 5) & 31;
  const int b = bid >> 10;
  const int kvh = h >> 2;           // H/KVH = 4
  const int q0 = qt * 64;

  const unsigned short* Qp = Q + ((size_t)b * NH + h) * S_ * DH;
  const unsigned short* Kp = Kb + ((size_t)b * NKV + kvh) * S_ * DH;
  const unsigned short* Vp = Vt + ((size_t)b * NKV + kvh) * DH * (size_t)S_;

  // Q fragments in registers: wave's 16 q-rows, A-layout [m=l15][k=quad*8+j]
  short8 qf[4];
  {
    const unsigned short* qp = Qp + (size_t)(q0 + wave * 16 + l15) * DH + quad * 8;
#pragma unroll
    for (int kk = 0; kk < 4; ++kk) qf[kk] = *(const short8*)(qp + kk * 32);
  }

  f32x4 of[8] = {};
  float mrow[4], lrow[4];
#pragma unroll
  for (int r = 0; r < 4; ++r) { mrow[r] = -1e30f; lrow[r] = 0.f; }

  const int jmax = q0 >> 7;
  const float scale = 0.08838834764831845f;  // 1/sqrt(128)
  unsigned short* Pw = &Ps[wave * 16 * 128];

  for (int j = 0; j <= jmax; ++j) {
    const int kv0 = j * 128;
    // stage K tile [kv][d] and V^T tile [d][kv]; slot = seg ^ (row&15)
#pragma unroll
    for (int r = 0; r < 8; ++r) {
      const int e = r * 256 + wave * 64 + lane;
      const int row = e >> 4, slot = e & 15;
      const int gseg = slot ^ (row & 15);
      async16(Kp + (size_t)(kv0 + row) * DH + gseg * 8, &Ks[(size_t)(r * 256 + wave * 64) * 8]);
    }
#pragma unroll
    for (int r = 0; r < 8; ++r) {
      const int e = r * 256 + wave * 64 + lane;
      const int row = e >> 4, slot = e & 15;
      const int gseg = slot ^ (row & 15);
      async16(Vp + (size_t)row * S_ + kv0 + gseg * 8, &Vs[(size_t)(r * 256 + wave * 64) * 8]);
    }
    __syncthreads();

    // S = Q K^T  (rows = wave's 16 q, cols = 128 kv)
    f32x4 sf[8];
#pragma unroll
    for (int ni = 0; ni < 8; ++ni) {
      f32x4 a = {};
#pragma unroll
      for (int kk = 0; kk < 4; ++kk) {
        const int rowi = ni * 16 + l15;
        short8 kf = *(const short8*)&Ks[rowi * 128 + ((kk * 4 + quad) ^ l15) * 8];
        a = __builtin_amdgcn_mfma_f32_16x16x32_bf16(qf[kk], kf, a, 0, 0, 0);
      }
      sf[ni] = a * scale;
    }

    if (j == jmax) {  // causal boundary tile
#pragma unroll
      for (int ni = 0; ni < 8; ++ni) {
        const int col = kv0 + ni * 16 + l15;
#pragma unroll
        for (int r = 0; r < 4; ++r) {
          const int row = q0 + wave * 16 + quad * 4 + r;
          if (col > row) sf[ni][r] = -1e30f;
        }
      }
    }

    // online softmax; row m = quad*4 + r, 16 lanes (l15) share a row
#pragma unroll
    for (int r = 0; r < 4; ++r) {
      float cm = sf[0][r];
#pragma unroll
      for (int ni = 1; ni < 8; ++ni) cm = fmaxf(cm, sf[ni][r]);
      cm = fmaxf(cm, __shfl_xor(cm, 1));
      cm = fmaxf(cm, __shfl_xor(cm, 2));
      cm = fmaxf(cm, __shfl_xor(cm, 4));
      cm = fmaxf(cm, __shfl_xor(cm, 8));
      const float nm = fmaxf(mrow[r], cm);
      const float alpha = __expf(mrow[r] - nm);
      mrow[r] = nm;
      float rs = 0.f;
#pragma unroll
      for (int ni = 0; ni < 8; ++ni) {
        const float p = __expf(sf[ni][r] - nm);
        sf[ni][r] = p;
        rs += p;
      }
      rs += __shfl_xor(rs, 1);
      rs += __shfl_xor(rs, 2);
      rs += __shfl_xor(rs, 4);
      rs += __shfl_xor(rs, 8);
      lrow[r] = lrow[r] * alpha + rs;
#pragma unroll
      for (int ni = 0; ni < 8; ++ni) of[ni][r] *= alpha;
    }

    // P (C-layout) -> LDS bf16 (swizzled), then read back as A-layout
#pragma unroll
    for (int ni = 0; ni < 8; ++ni) {
#pragma unroll
      for (int r = 0; r < 4; ++r) {
        const int pr = quad * 4 + r;
        const int c = ni * 16 + l15;
        const int slot = (c >> 3) ^ pr;
        Pw[pr * 128 + slot * 8 + (c & 7)] = f2bf(sf[ni][r]);
      }
    }
    short8 pf[4];
#pragma unroll
    for (int kk = 0; kk < 4; ++kk)
      pf[kk] = *(const short8*)&Pw[l15 * 128 + ((kk * 4 + quad) ^ l15) * 8];

    // O += P V   (B operand = V^T rows: [n=d][k=kv])
#pragma unroll
    for (int ni = 0; ni < 8; ++ni) {
#pragma unroll
      for (int kk = 0; kk < 4; ++kk) {
        const int rowi = ni * 16 + l15;
        short8 vf = *(const short8*)&Vs[rowi * 128 + ((kk * 4 + quad) ^ l15) * 8];
        of[ni] = __builtin_amdgcn_mfma_f32_16x16x32_bf16(pf[kk], vf, of[ni], 0, 0, 0);
      }
    }
    __syncthreads();  // before next tile overwrites Ks/Vs
  }

  float il[4];
#pragma unroll
  for (int r = 0; r < 4; ++r) il[r] = 1.0f / lrow[r];
#pragma unroll
  for (int ni = 0; ni < 8; ++ni) {
#pragma unroll
    for (int r = 0; r < 4; ++r) {
      const int row = q0 + wave * 16 + quad * 4 + r;
      const int d = ni * 16 + l15;
      O[(((size_t)b * S_ + row) * NH + h) * DH + d] = f2bf(of[ni][r] * il[r]);
    }
  }
}

extern "C" void kernel_launch(void* const* d_in, const int* in_sizes, int n_in,
                              void* d_out, int out_size, void* d_ws, size_t ws_size,
                              hipStream_t stream) {
  const float* hs = (const float*)d_in[0];
  // d_in[1] attention_mask: causal, applied analytically in k_attn
  const int* pos = (const int*)d_in[2];
  const float* Wq = (const float*)d_in[3];
  const float* bq = (const float*)d_in[4];
  const float* Wk = (const float*)d_in[5];
  const float* bk = (const float*)d_in[6];
  const float* Wv = (const float*)d_in[7];
  const float* bv = (const float*)d_in[8];
  const float* Wo = (const float*)d_in[9];
  float* out = (float*)d_out;

  // ws layout (128 MB):
  //   [0,32M):    X bf16 (4096x4096), reused as O (B,S,NH,D) after QKV GEMM
  //   [32M,80M):  WT bf16 (6144x4096) = [Wq^T;Wk^T;Wv^T], reused as Wo^T later
  //   [80M,112M): Q (B,NH,S,D)
  //   [112M,120M):K (B,NKV,S,D)
  //   [120M,128M):V^T (B,NKV,D,S)
  unsigned char* ws = (unsigned char*)d_ws;
  unsigned short* X   = (unsigned short*)(ws);
  unsigned short* WT  = (unsigned short*)(ws + 33554432ull);
  unsigned short* Qb  = (unsigned short*)(ws + 83886080ull);
  unsigned short* Kb  = (unsigned short*)(ws + 117440512ull);
  unsigned short* Vtb = (unsigned short*)(ws + 125829120ull);
  unsigned short* Ob  = X;    // reuse after QKV GEMM done reading X
  unsigned short* WoT = WT;   // reuse after QKV GEMM done reading WT

  dim3 tb(32, 8);
  k_cvt<<<16384, 256, 0, stream>>>((const float4*)hs, (ushort4*)X, 4194304);
  k_transpose<<<dim3(128, 128), tb, 0, stream>>>(Wq, WT, 4096, 4096);
  k_transpose<<<dim3(32, 128), tb, 0, stream>>>(Wk, WT + 4096ull * 4096ull, 4096, 1024);
  k_transpose<<<dim3(32, 128), tb, 0, stream>>>(Wv, WT + 5120ull * 4096ull, 4096, 1024);
  k_gemm<0><<<dim3(48, 32), 256, 0, stream>>>(X, WT, 4096, bq, bk, bv, Qb, Kb, Vtb, nullptr);
  k_transpose<<<dim3(128, 128), tb, 0, stream>>>(Wo, WoT, 4096, 4096);  // after QKV GEMM (region reuse)
  k_rope<<<32768, 256, 0, stream>>>(Qb, NH, pos);
  k_rope<<<8192, 256, 0, stream>>>(Kb, NKV, pos);
  k_attn<<<2048, 256, 0, stream>>>(Qb, Kb, Vtb, Ob);
  k_gemm<1><<<dim3(32, 32), 256, 0, stream>>>(Ob, WoT, 4096,
                                              nullptr, nullptr, nullptr,
                                              nullptr, nullptr, nullptr, out);
}

// Round 2
// 1075.936 us; speedup vs baseline: 1.0032x; 1.0032x over previous
//
#include <hip/hip_runtime.h>

#define B_ 2
#define S_ 2048
#define E_ 4096
#define NH 32
#define NKV 8
#define DH 128

typedef __attribute__((ext_vector_type(8))) short short8;   // 8 x bf16 (4 VGPRs)
typedef __attribute__((ext_vector_type(4))) float f32x4;    // MFMA 16x16 accumulator

__device__ __forceinline__ unsigned short f2bf(float f) {
  unsigned int u = __float_as_uint(f);
  u += 0x7fffu + ((u >> 16) & 1u);   // RNE
  return (unsigned short)(u >> 16);
}
__device__ __forceinline__ float bf2f(unsigned short u) {
  return __uint_as_float(((unsigned int)u) << 16);
}

// async global->LDS, 16B per lane. LDS dest = wave-uniform base + lane*16.
__device__ __forceinline__ void async16(const void* g, void* l) {
  __builtin_amdgcn_global_load_lds(
      (__attribute__((address_space(1))) void*)const_cast<void*>(g),
      (__attribute__((address_space(3))) void*)l, 16, 0, 0);
}

// ---------------- fp32 -> bf16 elementwise ----------------
__global__ void k_cvt(const float4* __restrict__ in, ushort4* __restrict__ out, int n4) {
  int i = blockIdx.x * blockDim.x + threadIdx.x;
  if (i >= n4) return;
  float4 v = in[i];
  ushort4 o;
  o.x = f2bf(v.x); o.y = f2bf(v.y); o.z = f2bf(v.z); o.w = f2bf(v.w);
  out[i] = o;
}

// ---------------- W (KxN fp32, row-major) -> out (NxK bf16) ----------------
__global__ void k_transpose(const float* __restrict__ in, unsigned short* __restrict__ out,
                            int K, int N) {
  __shared__ float tile[32][33];
  int n0 = blockIdx.x * 32, k0 = blockIdx.y * 32;
  int tx = threadIdx.x, ty = threadIdx.y;  // 32 x 8
#pragma unroll
  for (int j = 0; j < 32; j += 8)
    tile[ty + j][tx] = in[(size_t)(k0 + ty + j) * N + n0 + tx];
  __syncthreads();
#pragma unroll
  for (int j = 0; j < 32; j += 8)
    out[(size_t)(n0 + ty + j) * K + k0 + tx] = f2bf(tile[tx][ty + j]);
}

// ---------------- RoPE in-place on (B, heads, S, D) bf16 ----------------
__global__ void k_rope(unsigned short* buf, int heads, const int* __restrict__ pos) {
  int i = blockIdx.x * blockDim.x + threadIdx.x;
  int d = i & 63;
  int s = (i >> 6) & (S_ - 1);
  int bh = i >> 17;                 // S_*64 = 2^17 per (b,head)
  int b = bh / heads;
  float p = (float)pos[b * S_ + s];
  // inv_freq = 10000^(-d/64);  ln(10000)/64 = 0.14391156831212787
  float fr = p * expf(-0.14391156831212787f * (float)d);
  float c, sn;
  sincosf(fr, &sn, &c);
  size_t base = ((size_t)bh * S_ + s) * DH;
  float x1 = bf2f(buf[base + d]);
  float x2 = bf2f(buf[base + d + 64]);
  buf[base + d]      = f2bf(x1 * c - x2 * sn);
  buf[base + d + 64] = f2bf(x2 * c + x1 * sn);
}

// ---------------- GEMM: A(MxK bf16 row-major) x Bt(NxK bf16) ----------------
// LDS tiles are XOR-swizzled: global segment gseg = slot ^ (row&3) is loaded
// into LDS slot; fragment reads at slot' = quad ^ (l15&3) -> uniform 8 dw/bank
// (the wave64 b128 floor) instead of the un-swizzled 8-way conflict.
// 1D grid, m-major: m = bid % 32 (4096/128), n = bid / 32.
// MODE 0: QKV epilogue (bias + scatter to Q/K/V^T bf16).  MODE 1: plain fp32 C.
template <int MODE>
__global__ __launch_bounds__(256) void k_gemm(
    const unsigned short* __restrict__ A, const unsigned short* __restrict__ Bt, int K,
    const float* __restrict__ bq, const float* __restrict__ bk, const float* __restrict__ bv,
    unsigned short* __restrict__ Qo, unsigned short* __restrict__ Ko,
    unsigned short* __restrict__ Vo, float* __restrict__ Co) {
  __shared__ unsigned short As[128 * 32];
  __shared__ unsigned short Bs[128 * 32];
  const int tid = threadIdx.x;
  const int wave = tid >> 6, lane = tid & 63;
  const int l15 = lane & 15, quad = lane >> 4;
  const int bid = blockIdx.x;
  const int m0 = (bid & 31) * 128, n0 = (bid >> 5) * 128;
  const int wm = (wave & 1) * 64, wn = (wave >> 1) * 64;

  f32x4 acc[4][4] = {};
  const int e0 = wave * 64 + lane;
  const int sw = (quad ^ (l15 & 3)) * 8;   // swizzled fragment slot (elements)

  for (int k0 = 0; k0 < K; k0 += 32) {
#pragma unroll
    for (int r = 0; r < 2; ++r) {
      int e = r * 256 + e0;
      int row = e >> 2, slot = e & 3;
      int gseg = slot ^ (row & 3);
      async16(A + (size_t)(m0 + row) * K + k0 + gseg * 8, &As[(size_t)(r * 256 + wave * 64) * 8]);
      async16(Bt + (size_t)(n0 + row) * K + k0 + gseg * 8, &Bs[(size_t)(r * 256 + wave * 64) * 8]);
    }
    __syncthreads();
    short8 af[4], bfr[4];
#pragma unroll
    for (int i = 0; i < 4; ++i)
      af[i] = *(const short8*)&As[(wm + i * 16 + l15) * 32 + sw];
#pragma unroll
    for (int i = 0; i < 4; ++i)
      bfr[i] = *(const short8*)&Bs[(wn + i * 16 + l15) * 32 + sw];
#pragma unroll
    for (int mi = 0; mi < 4; ++mi)
#pragma unroll
      for (int ni = 0; ni < 4; ++ni)
        acc[mi][ni] = __builtin_amdgcn_mfma_f32_16x16x32_bf16(af[mi], bfr[ni], acc[mi][ni], 0, 0, 0);
    __syncthreads();
  }

#pragma unroll
  for (int mi = 0; mi < 4; ++mi) {
#pragma unroll
    for (int ni = 0; ni < 4; ++ni) {
      const int col = n0 + wn + ni * 16 + l15;
      const int rowb = m0 + wm + mi * 16 + quad * 4;
      if constexpr (MODE == 1) {
#pragma unroll
        for (int r = 0; r < 4; ++r)
          Co[(size_t)(rowb + r) * E_ + col] = acc[mi][ni][r];
      } else {
#pragma unroll
        for (int r = 0; r < 4; ++r) {
          const int row = rowb + r;
          const int b = row >> 11, s = row & (S_ - 1);
          float v = acc[mi][ni][r];
          if (col < 4096) {           // Q: (B,NH,S,D)
            v += bq[col];
            const int h = col >> 7, d = col & 127;
            Qo[(((size_t)b * NH + h) * S_ + s) * DH + d] = f2bf(v);
          } else if (col < 5120) {    // K: (B,NKV,S,D)
            const int t = col - 4096;
            v += bk[t];
            const int h = t >> 7, d = t & 127;
            Ko[(((size_t)b * NKV + h) * S_ + s) * DH + d] = f2bf(v);
          } else {                    // V^T: (B,NKV,D,S)
            const int t = col - 5120;
            v += bv[t];
            const int h = t >> 7, d = t & 127;
            Vo[(((size_t)b * NKV + h) * DH + d) * S_ + s] = f2bf(v);
          }
        }
      }
    }
  }
}

// ---------------- flash attention: Br=64, Bc=128, causal ----------------
// Q (B,NH,S,D), K (B,NKV,S,D), Vt (B,NKV,D,S) -> O (B,S,NH,D)   all bf16
__global__ __launch_bounds__(256) void k_attn(
    const unsigned short* __restrict__ Q, const unsigned short* __restrict__ Kb,
    const unsigned short* __restrict__ Vt, unsigned short* __restrict__ O) {
  __shared__ unsigned short Ks[128 * 128];  // 32KB, xor-swizzled 16B slots
  __shared__ unsigned short Vs[128 * 128];  // 32KB
  __shared__ unsigned short Ps[64 * 128];   // 16KB, per-wave 16 rows
  const int tid = threadIdx.x;
  const int wave = tid >> 6, lane = tid & 63;
  const int l15 = lane & 15, quad = lane >> 4;
  const int bid = blockIdx.x;
  const int qt = bid & 31;          // S/64
  const int h = (bid >> 5) & 31;
  const int b = bid >> 10;
  const int kvh = h >> 2;           // H/KVH = 4
  const int q0 = qt * 64;

  const unsigned short* Qp = Q + ((size_t)b * NH + h) * S_ * DH;
  const unsigned short* Kp = Kb + ((size_t)b * NKV + kvh) * S_ * DH;
  const unsigned short* Vp = Vt + ((size_t)b * NKV + kvh) * DH * (size_t)S_;

  // Q fragments in registers: wave's 16 q-rows, A-layout [m=l15][k=quad*8+j]
  short8 qf[4];
  {
    const unsigned short* qp = Qp + (size_t)(q0 + wave * 16 + l15) * DH + quad * 8;
#pragma unroll
    for (int kk = 0; kk < 4; ++kk) qf[kk] = *(const short8*)(qp + kk * 32);
  }

  f32x4 of[8] = {};
  float mrow[4], lrow[4];
#pragma unroll
  for (int r = 0; r < 4; ++r) { mrow[r] = -1e30f; lrow[r] = 0.f; }

  const int jmax = q0 >> 7;
  const float scale = 0.08838834764831845f;  // 1/sqrt(128)
  unsigned short* Pw = &Ps[wave * 16 * 128];

  for (int j = 0; j <= jmax; ++j) {
    const int kv0 = j * 128;
    // stage K tile [kv][d] and V^T tile [d][kv]; slot = seg ^ (row&15)
#pragma unroll
    for (int r = 0; r < 8; ++r) {
      const int e = r * 256 + wave * 64 + lane;
      const int row = e >> 4, slot = e & 15;
      const int gseg = slot ^ (row & 15);
      async16(Kp + (size_t)(kv0 + row) * DH + gseg * 8, &Ks[(size_t)(r * 256 + wave * 64) * 8]);
    }
#pragma unroll
    for (int r = 0; r < 8; ++r) {
      const int e = r * 256 + wave * 64 + lane;
      const int row = e >> 4, slot = e & 15;
      const int gseg = slot ^ (row & 15);
      async16(Vp + (size_t)row * S_ + kv0 + gseg * 8, &Vs[(size_t)(r * 256 + wave * 64) * 8]);
    }
    __syncthreads();

    // S = Q K^T  (rows = wave's 16 q, cols = 128 kv)
    f32x4 sf[8];
#pragma unroll
    for (int ni = 0; ni < 8; ++ni) {
      f32x4 a = {};
#pragma unroll
      for (int kk = 0; kk < 4; ++kk) {
        const int rowi = ni * 16 + l15;
        short8 kf = *(const short8*)&Ks[rowi * 128 + ((kk * 4 + quad) ^ l15) * 8];
        a = __builtin_amdgcn_mfma_f32_16x16x32_bf16(qf[kk], kf, a, 0, 0, 0);
      }
      sf[ni] = a * scale;
    }

    if (j == jmax) {  // causal boundary tile
#pragma unroll
      for (int ni = 0; ni < 8; ++ni) {
        const int col = kv0 + ni * 16 + l15;
#pragma unroll
        for (int r = 0; r < 4; ++r) {
          const int row = q0 + wave * 16 + quad * 4 + r;
          if (col > row) sf[ni][r] = -1e30f;
        }
      }
    }

    // online softmax; row m = quad*4 + r, 16 lanes (l15) share a row
#pragma unroll
    for (int r = 0; r < 4; ++r) {
      float cm = sf[0][r];
#pragma unroll
      for (int ni = 1; ni < 8; ++ni) cm = fmaxf(cm, sf[ni][r]);
      cm = fmaxf(cm, __shfl_xor(cm, 1));
      cm = fmaxf(cm, __shfl_xor(cm, 2));
      cm = fmaxf(cm, __shfl_xor(cm, 4));
      cm = fmaxf(cm, __shfl_xor(cm, 8));
      const float nm = fmaxf(mrow[r], cm);
      const float alpha = __expf(mrow[r] - nm);
      mrow[r] = nm;
      float rs = 0.f;
#pragma unroll
      for (int ni = 0; ni < 8; ++ni) {
        const float p = __expf(sf[ni][r] - nm);
        sf[ni][r] = p;
        rs += p;
      }
      rs += __shfl_xor(rs, 1);
      rs += __shfl_xor(rs, 2);
      rs += __shfl_xor(rs, 4);
      rs += __shfl_xor(rs, 8);
      lrow[r] = lrow[r] * alpha + rs;
#pragma unroll
      for (int ni = 0; ni < 8; ++ni) of[ni][r] *= alpha;
    }

    // P (C-layout) -> LDS bf16 (swizzled), then read back as A-layout.
    // P in [0,1]: truncating bf16 convert (1 VALU) is fine accuracy-wise.
#pragma unroll
    for (int ni = 0; ni < 8; ++ni) {
#pragma unroll
      for (int r = 0; r < 4; ++r) {
        const int pr = quad * 4 + r;
        const int c = ni * 16 + l15;
        const int slot = (c >> 3) ^ pr;
        Pw[pr * 128 + slot * 8 + (c & 7)] =
            (unsigned short)(__float_as_uint(sf[ni][r]) >> 16);
      }
    }
    short8 pf[4];
#pragma unroll
    for (int kk = 0; kk < 4; ++kk)
      pf[kk] = *(const short8*)&Pw[l15 * 128 + ((kk * 4 + quad) ^ l15) * 8];

    // O += P V   (B operand = V^T rows: [n=d][k=kv])
#pragma unroll
    for (int ni = 0; ni < 8; ++ni) {
#pragma unroll
      for (int kk = 0; kk < 4; ++kk) {
        const int rowi = ni * 16 + l15;
        short8 vf = *(const short8*)&Vs[rowi * 128 + ((kk * 4 + quad) ^ l15) * 8];
        of[ni] = __builtin_amdgcn_mfma_f32_16x16x32_bf16(pf[kk], vf, of[ni], 0, 0, 0);
      }
    }
    __syncthreads();  // before next tile overwrites Ks/Vs
  }

  float il[4];
#pragma unroll
  for (int r = 0; r < 4; ++r) il[r] = 1.0f / lrow[r];
#pragma unroll
  for (int ni = 0; ni < 8; ++ni) {
#pragma unroll
    for (int r = 0; r < 4; ++r) {
      const int row = q0 + wave * 16 + quad * 4 + r;
      const int d = ni * 16 + l15;
      O[(((size_t)b * S_ + row) * NH + h) * DH + d] = f2bf(of[ni][r] * il[r]);
    }
  }
}

extern "C" void kernel_launch(void* const* d_in, const int* in_sizes, int n_in,
                              void* d_out, int out_size, void* d_ws, size_t ws_size,
                              hipStream_t stream) {
  const float* hs = (const float*)d_in[0];
  // d_in[1] attention_mask: causal, applied analytically in k_attn
  const int* pos = (const int*)d_in[2];
  const float* Wq = (const float*)d_in[3];
  const float* bq = (const float*)d_in[4];
  const float* Wk = (const float*)d_in[5];
  const float* bk = (const float*)d_in[6];
  const float* Wv = (const float*)d_in[7];
  const float* bv = (const float*)d_in[8];
  const float* Wo = (const float*)d_in[9];
  float* out = (float*)d_out;

  // ws layout (128 MB):
  //   [0,32M):    X bf16 (4096x4096), reused as O (B,S,NH,D) after QKV GEMM
  //   [32M,80M):  WT bf16 (6144x4096) = [Wq^T;Wk^T;Wv^T], reused as Wo^T later
  //   [80M,112M): Q (B,NH,S,D)
  //   [112M,120M):K (B,NKV,S,D)
  //   [120M,128M):V^T (B,NKV,D,S)
  unsigned char* ws = (unsigned char*)d_ws;
  unsigned short* X   = (unsigned short*)(ws);
  unsigned short* WT  = (unsigned short*)(ws + 33554432ull);
  unsigned short* Qb  = (unsigned short*)(ws + 83886080ull);
  unsigned short* Kb  = (unsigned short*)(ws + 117440512ull);
  unsigned short* Vtb = (unsigned short*)(ws + 125829120ull);
  unsigned short* Ob  = X;    // reuse after QKV GEMM done reading X
  unsigned short* WoT = WT;   // reuse after QKV GEMM done reading WT

  dim3 tb(32, 8);
  k_cvt<<<16384, 256, 0, stream>>>((const float4*)hs, (ushort4*)X, 4194304);
  k_transpose<<<dim3(128, 128), tb, 0, stream>>>(Wq, WT, 4096, 4096);
  k_transpose<<<dim3(32, 128), tb, 0, stream>>>(Wk, WT + 4096ull * 4096ull, 4096, 1024);
  k_transpose<<<dim3(32, 128), tb, 0, stream>>>(Wv, WT + 5120ull * 4096ull, 4096, 1024);
  k_gemm<0><<<32 * 48, 256, 0, stream>>>(X, WT, 4096, bq, bk, bv, Qb, Kb, Vtb, nullptr);
  k_transpose<<<dim3(128, 128), tb, 0, stream>>>(Wo, WoT, 4096, 4096);  // after QKV GEMM (region reuse)
  k_rope<<<32768, 256, 0, stream>>>(Qb, NH, pos);
  k_rope<<<8192, 256, 0, stream>>>(Kb, NKV, pos);
  k_attn<<<2048, 256, 0, stream>>>(Qb, Kb, Vtb, Ob);
  k_gemm<1><<<32 * 32, 256, 0, stream>>>(Ob, WoT, 4096,
                                         nullptr, nullptr, nullptr,
                                         nullptr, nullptr, nullptr, out);
}

// Round 4
// 986.318 us; speedup vs baseline: 1.0943x; 1.0909x over previous
//
#include <hip/hip_runtime.h>

#define B_ 2
#define S_ 2048
#define E_ 4096
#define NH 32
#define NKV 8
#define DH 128

typedef __attribute__((ext_vector_type(8))) short short8;   // 8 x bf16 (4 VGPRs)
typedef __attribute__((ext_vector_type(4))) float f32x4;    // MFMA 16x16 accumulator

__device__ __forceinline__ unsigned short f2bf(float f) {
  unsigned int u = __float_as_uint(f);
  u += 0x7fffu + ((u >> 16) & 1u);   // RNE
  return (unsigned short)(u >> 16);
}
__device__ __forceinline__ float bf2f(unsigned short u) {
  return __uint_as_float(((unsigned int)u) << 16);
}

// async global->LDS, 16B per lane. LDS dest = wave-uniform base + lane*16.
__device__ __forceinline__ void async16(const void* g, void* l) {
  __builtin_amdgcn_global_load_lds(
      (__attribute__((address_space(1))) void*)const_cast<void*>(g),
      (__attribute__((address_space(3))) void*)l, 16, 0, 0);
}

// ---------------- fp32 -> bf16 elementwise ----------------
__global__ void k_cvt(const float4* __restrict__ in, ushort4* __restrict__ out, int n4) {
  int i = blockIdx.x * blockDim.x + threadIdx.x;
  if (i >= n4) return;
  float4 v = in[i];
  ushort4 o;
  o.x = f2bf(v.x); o.y = f2bf(v.y); o.z = f2bf(v.z); o.w = f2bf(v.w);
  out[i] = o;
}

// ---------------- W (KxN fp32, row-major) -> out (NxK bf16) ----------------
__global__ void k_transpose(const float* __restrict__ in, unsigned short* __restrict__ out,
                            int K, int N) {
  __shared__ float tile[32][33];
  int n0 = blockIdx.x * 32, k0 = blockIdx.y * 32;
  int tx = threadIdx.x, ty = threadIdx.y;  // 32 x 8
#pragma unroll
  for (int j = 0; j < 32; j += 8)
    tile[ty + j][tx] = in[(size_t)(k0 + ty + j) * N + n0 + tx];
  __syncthreads();
#pragma unroll
  for (int j = 0; j < 32; j += 8)
    out[(size_t)(n0 + ty + j) * K + k0 + tx] = f2bf(tile[tx][ty + j]);
}

// ---------------- RoPE in-place on (B, heads, S, D) bf16 ----------------
__global__ void k_rope(unsigned short* buf, int heads, const int* __restrict__ pos) {
  int i = blockIdx.x * blockDim.x + threadIdx.x;
  int d = i & 63;
  int s = (i >> 6) & (S_ - 1);
  int bh = i >> 17;                 // S_*64 = 2^17 per (b,head)
  int b = bh / heads;
  float p = (float)pos[b * S_ + s];
  // inv_freq = 10000^(-d/64);  ln(10000)/64 = 0.14391156831212787
  float fr = p * expf(-0.14391156831212787f * (float)d);
  float c, sn;
  sincosf(fr, &sn, &c);
  size_t base = ((size_t)bh * S_ + s) * DH;
  float x1 = bf2f(buf[base + d]);
  float x2 = bf2f(buf[base + d + 64]);
  buf[base + d]      = f2bf(x1 * c - x2 * sn);
  buf[base + d + 64] = f2bf(x2 * c + x1 * sn);
}

// ---------------- GEMM: A(MxK bf16 row-major) x Bt(NxK bf16) ----------------
// Double-buffered LDS, BK=32, ONE barrier per K-iter. Staging always targets
// buffer p^1 while reads target p -> the iter(i+1)-staging vs iter(i)-read WAR
// race of the single-buffer 2-barrier loop is structurally impossible (a wave
// can never be >1 barrier behind; barrier drains lgkm+vm). Prefetch overlaps
// with MFMA instead of being exposed between stage and barrier.
// Swizzle: global seg gseg = slot ^ (row&3) stored at slot; frag read at
// slot' = quad ^ (l15&3) -> uniform 8 dwords/bank (wave64 b128 floor).
// 1D grid, m-major: m = bid % 32, n = bid / 32.
// MODE 0: QKV epilogue (bias + scatter to Q/K/V^T bf16).  MODE 1: plain fp32 C.
template <int MODE>
__global__ __launch_bounds__(256) void k_gemm(
    const unsigned short* __restrict__ A, const unsigned short* __restrict__ Bt, int K,
    const float* __restrict__ bq, const float* __restrict__ bk, const float* __restrict__ bv,
    unsigned short* __restrict__ Qo, unsigned short* __restrict__ Ko,
    unsigned short* __restrict__ Vo, float* __restrict__ Co) {
  __shared__ unsigned short As[2][128 * 32];   // 2 x 8 KB
  __shared__ unsigned short Bs[2][128 * 32];   // 2 x 8 KB
  const int tid = threadIdx.x;
  const int wave = tid >> 6, lane = tid & 63;
  const int l15 = lane & 15, quad = lane >> 4;
  const int bid = blockIdx.x;
  const int m0 = (bid & 31) * 128, n0 = (bid >> 5) * 128;
  const int wm = (wave & 1) * 64, wn = (wave >> 1) * 64;

  f32x4 acc[4][4] = {};
  const int e0 = wave * 64 + lane;
  const int sw = (quad ^ (l15 & 3)) * 8;   // swizzled fragment slot (elements)

  auto stage = [&](int p, int k0) {
#pragma unroll
    for (int r = 0; r < 2; ++r) {
      int e = r * 256 + e0;
      int row = e >> 2, slot = e & 3;
      int gseg = slot ^ (row & 3);
      async16(A + (size_t)(m0 + row) * K + k0 + gseg * 8,
              &As[p][(size_t)(r * 256 + wave * 64) * 8]);
      async16(Bt + (size_t)(n0 + row) * K + k0 + gseg * 8,
              &Bs[p][(size_t)(r * 256 + wave * 64) * 8]);
    }
  };

  stage(0, 0);
  int p = 0;
  for (int k0 = 0; k0 < K; k0 += 32) {
    __syncthreads();                 // staging of buf p visible to all waves
    if (k0 + 32 < K) stage(p ^ 1, k0 + 32);   // prefetch next tile (other buf)
    short8 af[4], bfr[4];
#pragma unroll
    for (int i = 0; i < 4; ++i)
      af[i] = *(const short8*)&As[p][(wm + i * 16 + l15) * 32 + sw];
#pragma unroll
    for (int i = 0; i < 4; ++i)
      bfr[i] = *(const short8*)&Bs[p][(wn + i * 16 + l15) * 32 + sw];
#pragma unroll
    for (int mi = 0; mi < 4; ++mi)
#pragma unroll
      for (int ni = 0; ni < 4; ++ni)
        acc[mi][ni] = __builtin_amdgcn_mfma_f32_16x16x32_bf16(af[mi], bfr[ni], acc[mi][ni], 0, 0, 0);
    p ^= 1;
  }

#pragma unroll
  for (int mi = 0; mi < 4; ++mi) {
#pragma unroll
    for (int ni = 0; ni < 4; ++ni) {
      const int col = n0 + wn + ni * 16 + l15;
      const int rowb = m0 + wm + mi * 16 + quad * 4;
      if constexpr (MODE == 1) {
#pragma unroll
        for (int r = 0; r < 4; ++r)
          Co[(size_t)(rowb + r) * E_ + col] = acc[mi][ni][r];
      } else {
#pragma unroll
        for (int r = 0; r < 4; ++r) {
          const int row = rowb + r;
          const int b = row >> 11, s = row & (S_ - 1);
          float v = acc[mi][ni][r];
          if (col < 4096) {           // Q: (B,NH,S,D)
            v += bq[col];
            const int h = col >> 7, d = col & 127;
            Qo[(((size_t)b * NH + h) * S_ + s) * DH + d] = f2bf(v);
          } else if (col < 5120) {    // K: (B,NKV,S,D)
            const int t = col - 4096;
            v += bk[t];
            const int h = t >> 7, d = t & 127;
            Ko[(((size_t)b * NKV + h) * S_ + s) * DH + d] = f2bf(v);
          } else {                    // V^T: (B,NKV,D,S)
            const int t = col - 5120;
            v += bv[t];
            const int h = t >> 7, d = t & 127;
            Vo[(((size_t)b * NKV + h) * DH + d) * S_ + s] = f2bf(v);
          }
        }
      }
    }
  }
}

// ---------------- flash attention: Br=64, Bc=128, causal ----------------
// Q (B,NH,S,D), K (B,NKV,S,D), Vt (B,NKV,D,S) -> O (B,S,NH,D)   all bf16
__global__ __launch_bounds__(256) void k_attn(
    const unsigned short* __restrict__ Q, const unsigned short* __restrict__ Kb,
    const unsigned short* __restrict__ Vt, unsigned short* __restrict__ O) {
  __shared__ unsigned short Ks[128 * 128];  // 32KB, xor-swizzled 16B slots
  __shared__ unsigned short Vs[128 * 128];  // 32KB
  __shared__ unsigned short Ps[64 * 128];   // 16KB, per-wave 16 rows
  const int tid = threadIdx.x;
  const int wave = tid >> 6, lane = tid & 63;
  const int l15 = lane & 15, quad = lane >> 4;
  const int bid = blockIdx.x;
  const int qt = bid & 31;          // S/64
  const int h = (bid >> 5) & 31;
  const int b = bid >> 10;
  const int kvh = h >> 2;           // H/KVH = 4
  const int q0 = qt * 64;

  const unsigned short* Qp = Q + ((size_t)b * NH + h) * S_ * DH;
  const unsigned short* Kp = Kb + ((size_t)b * NKV + kvh) * S_ * DH;
  const unsigned short* Vp = Vt + ((size_t)b * NKV + kvh) * DH * (size_t)S_;

  // Q fragments in registers: wave's 16 q-rows, A-layout [m=l15][k=quad*8+j]
  short8 qf[4];
  {
    const unsigned short* qp = Qp + (size_t)(q0 + wave * 16 + l15) * DH + quad * 8;
#pragma unroll
    for (int kk = 0; kk < 4; ++kk) qf[kk] = *(const short8*)(qp + kk * 32);
  }

  f32x4 of[8] = {};
  float mrow[4], lrow[4];
#pragma unroll
  for (int r = 0; r < 4; ++r) { mrow[r] = -1e30f; lrow[r] = 0.f; }

  const int jmax = q0 >> 7;
  const float scale = 0.08838834764831845f;  // 1/sqrt(128)
  unsigned short* Pw = &Ps[wave * 16 * 128];

  for (int j = 0; j <= jmax; ++j) {
    const int kv0 = j * 128;
    // stage K tile [kv][d] and V^T tile [d][kv]; slot = seg ^ (row&15)
#pragma unroll
    for (int r = 0; r < 8; ++r) {
      const int e = r * 256 + wave * 64 + lane;
      const int row = e >> 4, slot = e & 15;
      const int gseg = slot ^ (row & 15);
      async16(Kp + (size_t)(kv0 + row) * DH + gseg * 8, &Ks[(size_t)(r * 256 + wave * 64) * 8]);
    }
#pragma unroll
    for (int r = 0; r < 8; ++r) {
      const int e = r * 256 + wave * 64 + lane;
      const int row = e >> 4, slot = e & 15;
      const int gseg = slot ^ (row & 15);
      async16(Vp + (size_t)row * S_ + kv0 + gseg * 8, &Vs[(size_t)(r * 256 + wave * 64) * 8]);
    }
    __syncthreads();

    // S = Q K^T  (rows = wave's 16 q, cols = 128 kv)
    f32x4 sf[8];
#pragma unroll
    for (int ni = 0; ni < 8; ++ni) {
      f32x4 a = {};
#pragma unroll
      for (int kk = 0; kk < 4; ++kk) {
        const int rowi = ni * 16 + l15;
        short8 kf = *(const short8*)&Ks[rowi * 128 + ((kk * 4 + quad) ^ l15) * 8];
        a = __builtin_amdgcn_mfma_f32_16x16x32_bf16(qf[kk], kf, a, 0, 0, 0);
      }
      sf[ni] = a * scale;
    }

    if (j == jmax) {  // causal boundary tile
#pragma unroll
      for (int ni = 0; ni < 8; ++ni) {
        const int col = kv0 + ni * 16 + l15;
#pragma unroll
        for (int r = 0; r < 4; ++r) {
          const int row = q0 + wave * 16 + quad * 4 + r;
          if (col > row) sf[ni][r] = -1e30f;
        }
      }
    }

    // online softmax; row m = quad*4 + r, 16 lanes (l15) share a row
#pragma unroll
    for (int r = 0; r < 4; ++r) {
      float cm = sf[0][r];
#pragma unroll
      for (int ni = 1; ni < 8; ++ni) cm = fmaxf(cm, sf[ni][r]);
      cm = fmaxf(cm, __shfl_xor(cm, 1));
      cm = fmaxf(cm, __shfl_xor(cm, 2));
      cm = fmaxf(cm, __shfl_xor(cm, 4));
      cm = fmaxf(cm, __shfl_xor(cm, 8));
      const float nm = fmaxf(mrow[r], cm);
      const float alpha = __expf(mrow[r] - nm);
      mrow[r] = nm;
      float rs = 0.f;
#pragma unroll
      for (int ni = 0; ni < 8; ++ni) {
        const float p = __expf(sf[ni][r] - nm);
        sf[ni][r] = p;
        rs += p;
      }
      rs += __shfl_xor(rs, 1);
      rs += __shfl_xor(rs, 2);
      rs += __shfl_xor(rs, 4);
      rs += __shfl_xor(rs, 8);
      lrow[r] = lrow[r] * alpha + rs;
#pragma unroll
      for (int ni = 0; ni < 8; ++ni) of[ni][r] *= alpha;
    }

    // P (C-layout) -> LDS bf16 (swizzled), then read back as A-layout.
    // P in [0,1]: truncating bf16 convert (1 VALU) is fine accuracy-wise.
#pragma unroll
    for (int ni = 0; ni < 8; ++ni) {
#pragma unroll
      for (int r = 0; r < 4; ++r) {
        const int pr = quad * 4 + r;
        const int c = ni * 16 + l15;
        const int slot = (c >> 3) ^ pr;
        Pw[pr * 128 + slot * 8 + (c & 7)] =
            (unsigned short)(__float_as_uint(sf[ni][r]) >> 16);
      }
    }
    short8 pf[4];
#pragma unroll
    for (int kk = 0; kk < 4; ++kk)
      pf[kk] = *(const short8*)&Pw[l15 * 128 + ((kk * 4 + quad) ^ l15) * 8];

    // O += P V   (B operand = V^T rows: [n=d][k=kv])
#pragma unroll
    for (int ni = 0; ni < 8; ++ni) {
#pragma unroll
      for (int kk = 0; kk < 4; ++kk) {
        const int rowi = ni * 16 + l15;
        short8 vf = *(const short8*)&Vs[rowi * 128 + ((kk * 4 + quad) ^ l15) * 8];
        of[ni] = __builtin_amdgcn_mfma_f32_16x16x32_bf16(pf[kk], vf, of[ni], 0, 0, 0);
      }
    }
    __syncthreads();  // before next tile overwrites Ks/Vs
  }

  float il[4];
#pragma unroll
  for (int r = 0; r < 4; ++r) il[r] = 1.0f / lrow[r];
#pragma unroll
  for (int ni = 0; ni < 8; ++ni) {
#pragma unroll
    for (int r = 0; r < 4; ++r) {
      const int row = q0 + wave * 16 + quad * 4 + r;
      const int d = ni * 16 + l15;
      O[(((size_t)b * S_ + row) * NH + h) * DH + d] = f2bf(of[ni][r] * il[r]);
    }
  }
}

extern "C" void kernel_launch(void* const* d_in, const int* in_sizes, int n_in,
                              void* d_out, int out_size, void* d_ws, size_t ws_size,
                              hipStream_t stream) {
  const float* hs = (const float*)d_in[0];
  // d_in[1] attention_mask: causal, applied analytically in k_attn
  const int* pos = (const int*)d_in[2];
  const float* Wq = (const float*)d_in[3];
  const float* bq = (const float*)d_in[4];
  const float* Wk = (const float*)d_in[5];
  const float* bk = (const float*)d_in[6];
  const float* Wv = (const float*)d_in[7];
  const float* bv = (const float*)d_in[8];
  const float* Wo = (const float*)d_in[9];
  float* out = (float*)d_out;

  // ws layout (128 MB):
  //   [0,32M):    X bf16 (4096x4096), reused as O (B,S,NH,D) after QKV GEMM
  //   [32M,80M):  WT bf16 (6144x4096) = [Wq^T;Wk^T;Wv^T], reused as Wo^T later
  //   [80M,112M): Q (B,NH,S,D)
  //   [112M,120M):K (B,NKV,S,D)
  //   [120M,128M):V^T (B,NKV,D,S)
  unsigned char* ws = (unsigned char*)d_ws;
  unsigned short* X   = (unsigned short*)(ws);
  unsigned short* WT  = (unsigned short*)(ws + 33554432ull);
  unsigned short* Qb  = (unsigned short*)(ws + 83886080ull);
  unsigned short* Kb  = (unsigned short*)(ws + 117440512ull);
  unsigned short* Vtb = (unsigned short*)(ws + 125829120ull);
  unsigned short* Ob  = X;    // reuse after QKV GEMM done reading X
  unsigned short* WoT = WT;   // reuse after QKV GEMM done reading WT

  dim3 tb(32, 8);
  k_cvt<<<16384, 256, 0, stream>>>((const float4*)hs, (ushort4*)X, 4194304);
  k_transpose<<<dim3(128, 128), tb, 0, stream>>>(Wq, WT, 4096, 4096);
  k_transpose<<<dim3(32, 128), tb, 0, stream>>>(Wk, WT + 4096ull * 4096ull, 4096, 1024);
  k_transpose<<<dim3(32, 128), tb, 0, stream>>>(Wv, WT + 5120ull * 4096ull, 4096, 1024);
  k_gemm<0><<<32 * 48, 256, 0, stream>>>(X, WT, 4096, bq, bk, bv, Qb, Kb, Vtb, nullptr);
  k_transpose<<<dim3(128, 128), tb, 0, stream>>>(Wo, WoT, 4096, 4096);  // after QKV GEMM (region reuse)
  k_rope<<<32768, 256, 0, stream>>>(Qb, NH, pos);
  k_rope<<<8192, 256, 0, stream>>>(Kb, NKV, pos);
  k_attn<<<2048, 256, 0, stream>>>(Qb, Kb, Vtb, Ob);
  k_gemm<1><<<32 * 32, 256, 0, stream>>>(Ob, WoT, 4096,
                                         nullptr, nullptr, nullptr,
                                         nullptr, nullptr, nullptr, out);
}